// Round 1
// baseline (2683.317 us; speedup 1.0000x reference)
//
#include <hip/hip_runtime.h>

#define N_USERS 50000
#define N_ENTITIES 100000
#define N_RELATIONS 16
#define N_EDGES 3200000
#define NNZ 2500000
#define CH 64

// ---------------------------------------------------------------------------
// init: entity_cur = entity_emb; out_entity = entity_emb; out_user = user_emb
// vectorized float4 copies.
// ---------------------------------------------------------------------------
__global__ void init_kernel(const float4* __restrict__ user_emb,
                            const float4* __restrict__ entity_emb,
                            float4* __restrict__ entity_cur,
                            float4* __restrict__ out_entity,
                            float4* __restrict__ out_user) {
    const int ne4 = N_ENTITIES * CH / 4;  // 1.6M
    const int nu4 = N_USERS * CH / 4;     // 0.8M
    int i = blockIdx.x * blockDim.x + threadIdx.x;
    if (i < ne4) {
        float4 v = entity_emb[i];
        entity_cur[i] = v;
        out_entity[i] = v;
    }
    if (i < nu4) {
        out_user[i] = user_emb[i];
    }
}

// ---------------------------------------------------------------------------
// KG aggregate: one lane per (edge, channel). 64 lanes of a wave share one
// edge -> index/mask loads are wave-uniform (L1 broadcast); row accesses are
// 256B contiguous per wave (fully coalesced).
// ---------------------------------------------------------------------------
__global__ void kg_agg_kernel(const float* __restrict__ entity_cur,
                              const float* __restrict__ weight,
                              const float* __restrict__ mask,
                              const int* __restrict__ edge_head,
                              const int* __restrict__ edge_tail,
                              const int* __restrict__ edge_type,
                              float* __restrict__ entity_agg) {
    int gid = blockIdx.x * blockDim.x + threadIdx.x;  // < 3.2M*64 = 204.8M
    int e = gid >> 6;
    int ch = gid & 63;
    if (e >= N_EDGES) return;
    int t = edge_tail[e];
    int h = edge_head[e];
    int r = edge_type[e] - 1;
    float m = mask[e];
    float v = entity_cur[t * CH + ch] * m * weight[r * CH + ch];
    atomicAdd(&entity_agg[h * CH + ch], v);
}

// ---------------------------------------------------------------------------
// User aggregate: interact_mat (COO) @ entity_cur, scatter to user rows.
// ---------------------------------------------------------------------------
__global__ void user_agg_kernel(const float* __restrict__ entity_cur,
                                const float* __restrict__ vals,
                                const int* __restrict__ rows,
                                const int* __restrict__ cols,
                                float* __restrict__ user_agg) {
    int gid = blockIdx.x * blockDim.x + threadIdx.x;  // < 2.5M*64 = 160M
    int e = gid >> 6;
    int ch = gid & 63;
    if (e >= NNZ) return;
    int c = cols[e];
    int rrow = rows[e];
    float v = vals[e] * entity_cur[c * CH + ch];
    atomicAdd(&user_agg[rrow * CH + ch], v);
}

// ---------------------------------------------------------------------------
// L2-normalize each 64-float row (one wave per row, butterfly shuffle),
// write normalized value to cur (optional) and accumulate into res.
// ---------------------------------------------------------------------------
__global__ void norm_add_kernel(const float* __restrict__ agg,
                                float* __restrict__ cur,   // may be nullptr
                                float* __restrict__ res,
                                int nrows) {
    int gid = blockIdx.x * blockDim.x + threadIdx.x;
    int row = gid >> 6;
    int lane = threadIdx.x & 63;
    if (row >= nrows) return;
    float x = agg[row * CH + lane];
    float s = x * x;
    #pragma unroll
    for (int off = 32; off > 0; off >>= 1)
        s += __shfl_xor(s, off, 64);
    float n = sqrtf(s);
    float y = x / fmaxf(n, 1e-12f);
    if (cur) cur[row * CH + lane] = y;
    res[row * CH + lane] += y;
}

extern "C" void kernel_launch(void* const* d_in, const int* in_sizes, int n_in,
                              void* d_out, int out_size, void* d_ws, size_t ws_size,
                              hipStream_t stream) {
    const float* user_emb   = (const float*)d_in[0];
    const float* entity_emb = (const float*)d_in[1];
    const float* weight     = (const float*)d_in[2];
    const float* mask       = (const float*)d_in[3];
    const float* ivals      = (const float*)d_in[4];
    const int*   edge_head  = (const int*)d_in[5];
    const int*   edge_tail  = (const int*)d_in[6];
    const int*   edge_type  = (const int*)d_in[7];
    const int*   irows      = (const int*)d_in[8];
    const int*   icols      = (const int*)d_in[9];

    float* out_entity = (float*)d_out;                      // [N_ENTITIES*CH]
    float* out_user   = (float*)d_out + N_ENTITIES * CH;    // [N_USERS*CH]

    float* entity_agg = (float*)d_ws;                                   // 6.4M floats
    float* user_agg   = entity_agg + (size_t)N_ENTITIES * CH;           // 3.2M floats
    float* entity_cur = user_agg + (size_t)N_USERS * CH;                // 6.4M floats

    // init: copies of embeddings into residuals + current entity state
    {
        int n4 = N_ENTITIES * CH / 4;  // 1.6M (covers user too: 0.8M)
        int blocks = (n4 + 255) / 256;
        init_kernel<<<blocks, 256, 0, stream>>>(
            (const float4*)user_emb, (const float4*)entity_emb,
            (float4*)entity_cur, (float4*)out_entity, (float4*)out_user);
    }

    for (int hop = 0; hop < 2; hop++) {
        hipMemsetAsync(entity_agg, 0, (size_t)N_ENTITIES * CH * sizeof(float), stream);
        hipMemsetAsync(user_agg,   0, (size_t)N_USERS * CH * sizeof(float), stream);

        {
            long long total = (long long)N_EDGES * 64;
            int blocks = (int)((total + 255) / 256);  // 800000
            kg_agg_kernel<<<blocks, 256, 0, stream>>>(
                entity_cur, weight, mask, edge_head, edge_tail, edge_type, entity_agg);
        }
        {
            long long total = (long long)NNZ * 64;
            int blocks = (int)((total + 255) / 256);  // 625000
            user_agg_kernel<<<blocks, 256, 0, stream>>>(
                entity_cur, ivals, irows, icols, user_agg);
        }
        {
            int blocks = (N_ENTITIES * 64) / 256;  // 25000
            norm_add_kernel<<<blocks, 256, 0, stream>>>(
                entity_agg, entity_cur, out_entity, N_ENTITIES);
        }
        {
            int blocks = (N_USERS * 64) / 256;  // 12500
            norm_add_kernel<<<blocks, 256, 0, stream>>>(
                user_agg, nullptr, out_user, N_USERS);
        }
    }
}

// Round 2
// 1726.197 us; speedup vs baseline: 1.5545x; 1.5545x over previous
//
#include <hip/hip_runtime.h>

#define N_USERS 50000
#define N_ENTITIES 100000
#define N_RELATIONS 16
#define N_EDGES 3200000
#define NNZ 2500000
#define CH 64

// ---------------------------------------------------------------------------
// init: out_entity = entity_emb; out_user = user_emb; entA = entity_emb
// ---------------------------------------------------------------------------
__global__ void init_kernel(const float4* __restrict__ user_emb,
                            const float4* __restrict__ entity_emb,
                            float4* __restrict__ entity_cur,
                            float4* __restrict__ out_entity,
                            float4* __restrict__ out_user) {
    const int ne4 = N_ENTITIES * CH / 4;  // 1.6M
    const int nu4 = N_USERS * CH / 4;     // 0.8M
    int i = blockIdx.x * blockDim.x + threadIdx.x;
    if (i < ne4) {
        float4 v = entity_emb[i];
        entity_cur[i] = v;
        out_entity[i] = v;
    }
    if (i < nu4) {
        out_user[i] = user_emb[i];
    }
}

// ---------------------------------------------------------------------------
// CSR build: histogram -> single-block scan (writes row_ptr AND cursor) ->
// scatter packed edge payloads.
// ---------------------------------------------------------------------------
__global__ void hist_kernel(const int* __restrict__ idx, int* __restrict__ counts, int n) {
    int i = blockIdx.x * blockDim.x + threadIdx.x;
    if (i < n) atomicAdd(&counts[idx[i]], 1);
}

// single block, 1024 threads. counts_cursor: in = counts, out = cursor (=row start)
__global__ void scan_kernel(int* __restrict__ counts_cursor, int* __restrict__ row_ptr, int n) {
    __shared__ int partials[1024];
    int t = threadIdx.x;
    int chunk = (n + 1023) >> 10;
    int begin = t * chunk;
    int end = min(begin + chunk, n);
    int s = 0;
    for (int i = begin; i < end; ++i) s += counts_cursor[i];
    partials[t] = s;
    __syncthreads();
    // Hillis-Steele inclusive scan over 1024 partials
    for (int d = 1; d < 1024; d <<= 1) {
        int v = (t >= d) ? partials[t - d] : 0;
        __syncthreads();
        partials[t] += v;
        __syncthreads();
    }
    int off = partials[t] - s;  // exclusive prefix of this thread's chunk
    for (int i = begin; i < end; ++i) {
        int c = counts_cursor[i];
        row_ptr[i] = off;
        counts_cursor[i] = off;  // becomes the scatter cursor
        off += c;
    }
    if (t == 1023) row_ptr[n] = off;  // total
}

// KG edges: payload = (tail | rel<<20, mask). tail < 2^17, rel in [0,16).
__global__ void kg_scatter_kernel(const int* __restrict__ head,
                                  const int* __restrict__ tail,
                                  const int* __restrict__ type,
                                  const float* __restrict__ mask,
                                  int* __restrict__ cursor,
                                  int2* __restrict__ packed) {
    int e = blockIdx.x * blockDim.x + threadIdx.x;
    if (e >= N_EDGES) return;
    int h = head[e];
    int pos = atomicAdd(&cursor[h], 1);
    packed[pos] = make_int2(tail[e] | ((type[e] - 1) << 20), __float_as_int(mask[e]));
}

// Interaction nnz: payload = (col, val)
__global__ void usr_scatter_kernel(const int* __restrict__ rows,
                                   const int* __restrict__ cols,
                                   const float* __restrict__ vals,
                                   int* __restrict__ cursor,
                                   int2* __restrict__ packed) {
    int e = blockIdx.x * blockDim.x + threadIdx.x;
    if (e >= NNZ) return;
    int r = rows[e];
    int pos = atomicAdd(&cursor[r], 1);
    packed[pos] = make_int2(cols[e], __float_as_int(vals[e]));
}

// ---------------------------------------------------------------------------
// KG aggregation, CSR form: one wave per head entity, lane = channel.
// Fused L2-normalize + residual accumulate. Zero float atomics.
// ---------------------------------------------------------------------------
__global__ void kg_agg_csr_kernel(const float* __restrict__ cur,
                                  const float* __restrict__ weight,
                                  const int* __restrict__ row_ptr,
                                  const int2* __restrict__ packed,
                                  float* __restrict__ nxt,
                                  float* __restrict__ res) {
    __shared__ float wlds[N_RELATIONS * CH];  // 4 KB
    for (int i = threadIdx.x; i < N_RELATIONS * CH; i += blockDim.x)
        wlds[i] = weight[i];
    __syncthreads();

    int wid = (blockIdx.x * blockDim.x + threadIdx.x) >> 6;  // head row
    int lane = threadIdx.x & 63;
    if (wid >= N_ENTITIES) return;
    int s = row_ptr[wid];
    int e = row_ptr[wid + 1];
    float acc = 0.f;
    int i = s;
    for (; i + 1 < e; i += 2) {  // 2-way unroll: two independent gathers in flight
        int2 p0 = packed[i];
        int2 p1 = packed[i + 1];
        float g0 = cur[(p0.x & 0xFFFFF) * CH + lane];
        float g1 = cur[(p1.x & 0xFFFFF) * CH + lane];
        acc += g0 * __int_as_float(p0.y) * wlds[((p0.x >> 20) & 15) * CH + lane];
        acc += g1 * __int_as_float(p1.y) * wlds[((p1.x >> 20) & 15) * CH + lane];
    }
    if (i < e) {
        int2 p = packed[i];
        float g = cur[(p.x & 0xFFFFF) * CH + lane];
        acc += g * __int_as_float(p.y) * wlds[((p.x >> 20) & 15) * CH + lane];
    }
    // fused L2 normalize (wave butterfly) + residual add
    float ss = acc * acc;
    #pragma unroll
    for (int off = 32; off > 0; off >>= 1) ss += __shfl_xor(ss, off, 64);
    float y = acc / fmaxf(sqrtf(ss), 1e-12f);
    nxt[wid * CH + lane] = y;
    res[wid * CH + lane] += y;
}

// ---------------------------------------------------------------------------
// User aggregation, CSR form: one wave per user row. Fused normalize+residual.
// ---------------------------------------------------------------------------
__global__ void usr_agg_csr_kernel(const float* __restrict__ cur,
                                   const int* __restrict__ row_ptr,
                                   const int2* __restrict__ packed,
                                   float* __restrict__ res) {
    int wid = (blockIdx.x * blockDim.x + threadIdx.x) >> 6;  // user row
    int lane = threadIdx.x & 63;
    if (wid >= N_USERS) return;
    int s = row_ptr[wid];
    int e = row_ptr[wid + 1];
    float acc = 0.f;
    int i = s;
    for (; i + 1 < e; i += 2) {
        int2 p0 = packed[i];
        int2 p1 = packed[i + 1];
        float g0 = cur[p0.x * CH + lane];
        float g1 = cur[p1.x * CH + lane];
        acc += g0 * __int_as_float(p0.y);
        acc += g1 * __int_as_float(p1.y);
    }
    if (i < e) {
        int2 p = packed[i];
        acc += cur[p.x * CH + lane] * __int_as_float(p.y);
    }
    float ss = acc * acc;
    #pragma unroll
    for (int off = 32; off > 0; off >>= 1) ss += __shfl_xor(ss, off, 64);
    float y = acc / fmaxf(sqrtf(ss), 1e-12f);
    res[wid * CH + lane] += y;
}

extern "C" void kernel_launch(void* const* d_in, const int* in_sizes, int n_in,
                              void* d_out, int out_size, void* d_ws, size_t ws_size,
                              hipStream_t stream) {
    const float* user_emb   = (const float*)d_in[0];
    const float* entity_emb = (const float*)d_in[1];
    const float* weight     = (const float*)d_in[2];
    const float* mask       = (const float*)d_in[3];
    const float* ivals      = (const float*)d_in[4];
    const int*   edge_head  = (const int*)d_in[5];
    const int*   edge_tail  = (const int*)d_in[6];
    const int*   edge_type  = (const int*)d_in[7];
    const int*   irows      = (const int*)d_in[8];
    const int*   icols      = (const int*)d_in[9];

    float* out_entity = (float*)d_out;                    // [N_ENTITIES*CH]
    float* out_user   = (float*)d_out + (size_t)N_ENTITIES * CH;

    // workspace layout (all 8B-aligned)
    float* entA       = (float*)d_ws;                                 // 6.4M f
    float* entB       = entA + (size_t)N_ENTITIES * CH;               // 6.4M f
    int2*  ent_packed = (int2*)(entB + (size_t)N_ENTITIES * CH);      // 3.2M int2
    int2*  usr_packed = ent_packed + (size_t)N_EDGES;                 // 2.5M int2
    int*   ent_cnt    = (int*)(usr_packed + (size_t)NNZ);             // 100000 (counts -> cursor)
    int*   ent_rp     = ent_cnt + N_ENTITIES;                         // 100001
    int*   usr_cnt    = ent_rp + N_ENTITIES + 1;                      // 50000 (counts -> cursor)
    int*   usr_rp     = usr_cnt + N_USERS;                            // 50001

    // ---- build CSRs (identical for both hops: build once) ----
    hipMemsetAsync(ent_cnt, 0, (size_t)N_ENTITIES * sizeof(int), stream);
    hipMemsetAsync(usr_cnt, 0, (size_t)N_USERS * sizeof(int), stream);

    hist_kernel<<<(N_EDGES + 255) / 256, 256, 0, stream>>>(edge_head, ent_cnt, N_EDGES);
    hist_kernel<<<(NNZ + 255) / 256, 256, 0, stream>>>(irows, usr_cnt, NNZ);

    scan_kernel<<<1, 1024, 0, stream>>>(ent_cnt, ent_rp, N_ENTITIES);
    scan_kernel<<<1, 1024, 0, stream>>>(usr_cnt, usr_rp, N_USERS);

    kg_scatter_kernel<<<(N_EDGES + 255) / 256, 256, 0, stream>>>(
        edge_head, edge_tail, edge_type, mask, ent_cnt, ent_packed);
    usr_scatter_kernel<<<(NNZ + 255) / 256, 256, 0, stream>>>(
        irows, icols, ivals, usr_cnt, usr_packed);

    // ---- init residuals + current state ----
    {
        int n4 = N_ENTITIES * CH / 4;
        init_kernel<<<(n4 + 255) / 256, 256, 0, stream>>>(
            (const float4*)user_emb, (const float4*)entity_emb,
            (float4*)entA, (float4*)out_entity, (float4*)out_user);
    }

    // ---- 2 hops, double-buffered entity state ----
    float* cur = entA;
    float* nxt = entB;
    for (int hop = 0; hop < 2; hop++) {
        kg_agg_csr_kernel<<<N_ENTITIES * CH / 256, 256, 0, stream>>>(
            cur, weight, ent_rp, ent_packed, nxt, out_entity);
        usr_agg_csr_kernel<<<N_USERS * CH / 256, 256, 0, stream>>>(
            cur, usr_rp, usr_packed, out_user);
        float* t = cur; cur = nxt; nxt = t;
    }
}

// Round 3
// 1264.752 us; speedup vs baseline: 2.1216x; 1.3649x over previous
//
#include <hip/hip_runtime.h>

#define N_USERS 50000
#define N_ENTITIES 100000
#define N_RELATIONS 16
#define N_EDGES 3200000
#define NNZ 2500000
#define CH 64

#define NBUCK_E 391   // ceil(100000/256)
#define NBUCK_U 196   // ceil(50000/256)
#define CHUNK_E 391   // ceil(100000/256) elements per scan block
#define CHUNK_U 196

// ---------------------------------------------------------------------------
// init: out_entity = entity_emb; out_user = user_emb; entA = entity_emb
// ---------------------------------------------------------------------------
__global__ void init_kernel(const float4* __restrict__ user_emb,
                            const float4* __restrict__ entity_emb,
                            float4* __restrict__ entity_cur,
                            float4* __restrict__ out_entity,
                            float4* __restrict__ out_user) {
    const int ne4 = N_ENTITIES * CH / 4;
    const int nu4 = N_USERS * CH / 4;
    int i = blockIdx.x * blockDim.x + threadIdx.x;
    if (i < ne4) {
        float4 v = entity_emb[i];
        entity_cur[i] = v;
        out_entity[i] = v;
    }
    if (i < nu4) out_user[i] = user_emb[i];
}

// ---------------------------------------------------------------------------
// fine histogram (per destination row)
// ---------------------------------------------------------------------------
__global__ void hist_kernel(const int* __restrict__ idx, int* __restrict__ counts, int n) {
    int i = blockIdx.x * blockDim.x + threadIdx.x;
    if (i < n) atomicAdd(&counts[idx[i]], 1);
}

// bucket counts = sum of 256 fine counts (one block per bucket)
__global__ void bucket_sum_kernel(const int* __restrict__ fine, int* __restrict__ bcnt, int nfine) {
    int i = (blockIdx.x << 8) + threadIdx.x;
    int v = (i < nfine) ? fine[i] : 0;
    __shared__ int red[256];
    red[threadIdx.x] = v;
    __syncthreads();
    for (int d = 128; d; d >>= 1) {
        if (threadIdx.x < (unsigned)d) red[threadIdx.x] += red[threadIdx.x + d];
        __syncthreads();
    }
    if (threadIdx.x == 0) bcnt[blockIdx.x] = red[0];
}

// ---------------------------------------------------------------------------
// hierarchical exclusive scan: A) block partial sums, B) scan partials
// (single block), C) per-block fixup writing row_ptr.
// ---------------------------------------------------------------------------
__global__ void scan_partA(const int* __restrict__ in, int* __restrict__ partials,
                           int n, int chunk) {
    int base = blockIdx.x * chunk;
    int lim = min(base + chunk, n);
    int s = 0;
    for (int i = base + (int)threadIdx.x; i < lim; i += 256) s += in[i];
    __shared__ int red[256];
    red[threadIdx.x] = s;
    __syncthreads();
    for (int d = 128; d; d >>= 1) {
        if (threadIdx.x < (unsigned)d) red[threadIdx.x] += red[threadIdx.x + d];
        __syncthreads();
    }
    if (threadIdx.x == 0) partials[blockIdx.x] = red[0];
}

__global__ void scan_partB(int* __restrict__ partials, int* __restrict__ row_ptr_n, int total) {
    __shared__ int lds[256];
    int t = threadIdx.x;
    int v = partials[t];
    lds[t] = v;
    __syncthreads();
    for (int d = 1; d < 256; d <<= 1) {
        int u = (t >= d) ? lds[t - d] : 0;
        __syncthreads();
        lds[t] += u;
        __syncthreads();
    }
    partials[t] = lds[t] - v;  // exclusive
    if (t == 0) *row_ptr_n = total;
}

__global__ void scan_partC(const int* __restrict__ in, const int* __restrict__ partials,
                           int* __restrict__ row_ptr, int n, int chunk) {
    int base = blockIdx.x * chunk;
    int lim = min(base + chunk, n);
    __shared__ int tile[256];
    __shared__ int carry_s;
    if (threadIdx.x == 0) carry_s = partials[blockIdx.x];
    __syncthreads();
    for (int t0 = base; t0 < lim; t0 += 256) {
        int i = t0 + (int)threadIdx.x;
        int v = (i < lim) ? in[i] : 0;
        int carry = carry_s;
        tile[threadIdx.x] = v;
        __syncthreads();
        for (int d = 1; d < 256; d <<= 1) {
            int u = (threadIdx.x >= (unsigned)d) ? tile[threadIdx.x - d] : 0;
            __syncthreads();
            tile[threadIdx.x] += u;
            __syncthreads();
        }
        int incl = tile[threadIdx.x];
        if (i < lim) row_ptr[i] = carry + incl - v;
        __syncthreads();
        if (threadIdx.x == 255) carry_s = carry + incl;
        __syncthreads();
    }
}

// single-block scan for <=512 buckets: writes bucket row_ptr AND working cursor
__global__ void small_scan(const int* __restrict__ cnt, int* __restrict__ rp,
                           int* __restrict__ cur, int n) {
    __shared__ int lds[512];
    int t = threadIdx.x;
    int v = (t < n) ? cnt[t] : 0;
    lds[t] = v;
    __syncthreads();
    for (int d = 1; d < 512; d <<= 1) {
        int u = (t >= d) ? lds[t - d] : 0;
        __syncthreads();
        lds[t] += u;
        __syncthreads();
    }
    int excl = lds[t] - v;
    if (t < n) { rp[t] = excl; cur[t] = excl; }
    if (t == n - 1) rp[n] = excl + v;
}

// ---------------------------------------------------------------------------
// pass 1: bin edges into ~400 coarse buckets (key >> 8). Per-block LDS
// histogram -> one global atomic per (block,bucket) -> contiguous runs from a
// single block (single XCD) => low write amplification.
// ---------------------------------------------------------------------------
__global__ void kg_pass1(const int* __restrict__ head, const int* __restrict__ tail,
                         const int* __restrict__ type, const float* __restrict__ mask,
                         int* __restrict__ gcur,
                         int* __restrict__ bk, int* __restrict__ ba, int* __restrict__ bb,
                         int chunk) {
    __shared__ int hist[400];
    __shared__ int lbase[400];
    for (int i = threadIdx.x; i < 400; i += blockDim.x) hist[i] = 0;
    __syncthreads();
    int base = blockIdx.x * chunk;
    int lim = min(base + chunk, N_EDGES);
    for (int i = base + (int)threadIdx.x; i < lim; i += blockDim.x)
        atomicAdd(&hist[head[i] >> 8], 1);
    __syncthreads();
    for (int i = threadIdx.x; i < 400; i += blockDim.x) {
        int c = hist[i];
        lbase[i] = c ? atomicAdd(&gcur[i], c) : 0;
        hist[i] = 0;  // becomes local cursor
    }
    __syncthreads();
    for (int i = base + (int)threadIdx.x; i < lim; i += blockDim.x) {
        int h = head[i];
        int b = h >> 8;
        int pos = lbase[b] + atomicAdd(&hist[b], 1);
        bk[pos] = h;
        ba[pos] = tail[i] | ((type[i] - 1) << 20);
        bb[pos] = __float_as_int(mask[i]);
    }
}

__global__ void usr_pass1(const int* __restrict__ rows, const int* __restrict__ cols,
                          const float* __restrict__ vals,
                          int* __restrict__ gcur,
                          int* __restrict__ bk, int* __restrict__ ba, int* __restrict__ bb,
                          int chunk) {
    __shared__ int hist[400];
    __shared__ int lbase[400];
    for (int i = threadIdx.x; i < 400; i += blockDim.x) hist[i] = 0;
    __syncthreads();
    int base = blockIdx.x * chunk;
    int lim = min(base + chunk, NNZ);
    for (int i = base + (int)threadIdx.x; i < lim; i += blockDim.x)
        atomicAdd(&hist[rows[i] >> 8], 1);
    __syncthreads();
    for (int i = threadIdx.x; i < 400; i += blockDim.x) {
        int c = hist[i];
        lbase[i] = c ? atomicAdd(&gcur[i], c) : 0;
        hist[i] = 0;
    }
    __syncthreads();
    for (int i = base + (int)threadIdx.x; i < lim; i += blockDim.x) {
        int r = rows[i];
        int b = r >> 8;
        int pos = lbase[b] + atomicAdd(&hist[b], 1);
        bk[pos] = r;
        ba[pos] = cols[i];
        bb[pos] = __float_as_int(vals[i]);
    }
}

// ---------------------------------------------------------------------------
// pass 2: one block per bucket; per-row cursors live in LDS (no global
// atomics); all writes go to this bucket's contiguous destination window.
// ---------------------------------------------------------------------------
__global__ void bin_pass2(const int* __restrict__ bk, const int* __restrict__ ba,
                          const int* __restrict__ bb,
                          const int* __restrict__ bucket_rp,
                          const int* __restrict__ row_ptr, int nrows,
                          int2* __restrict__ packed) {
    __shared__ int cur[256];
    int b = blockIdx.x;
    int rbase = b << 8;
    int t = threadIdx.x;
    if (t < 256) cur[t] = (rbase + t < nrows) ? row_ptr[rbase + t] : 0;
    __syncthreads();
    int s = bucket_rp[b], e = bucket_rp[b + 1];
    for (int i = s + t; i < e; i += blockDim.x) {
        int k = bk[i];
        int pos = atomicAdd(&cur[k & 255], 1);
        packed[pos] = make_int2(ba[i], bb[i]);
    }
}

// ---------------------------------------------------------------------------
// merged aggregation: one wave per destination row (entities then users),
// 4-way unrolled gathers, fused L2-normalize + residual add. No float atomics.
// ---------------------------------------------------------------------------
__global__ void agg_kernel(const float* __restrict__ cur,
                           const float* __restrict__ weight,
                           const int* __restrict__ ent_rp, const int2* __restrict__ ent_packed,
                           const int* __restrict__ usr_rp, const int2* __restrict__ usr_packed,
                           float* __restrict__ nxt,
                           float* __restrict__ res_ent, float* __restrict__ res_usr) {
    __shared__ float wlds[N_RELATIONS * CH];  // 4 KB
    for (int i = threadIdx.x; i < N_RELATIONS * CH; i += blockDim.x)
        wlds[i] = weight[i];
    __syncthreads();

    int gwid = (blockIdx.x * blockDim.x + threadIdx.x) >> 6;
    int lane = threadIdx.x & 63;

    if (gwid < N_ENTITIES) {
        int s = ent_rp[gwid], e = ent_rp[gwid + 1];
        float acc = 0.f;
        int i = s;
        for (; i + 3 < e; i += 4) {
            int2 p0 = ent_packed[i];
            int2 p1 = ent_packed[i + 1];
            int2 p2 = ent_packed[i + 2];
            int2 p3 = ent_packed[i + 3];
            float g0 = cur[(p0.x & 0xFFFFF) * CH + lane];
            float g1 = cur[(p1.x & 0xFFFFF) * CH + lane];
            float g2 = cur[(p2.x & 0xFFFFF) * CH + lane];
            float g3 = cur[(p3.x & 0xFFFFF) * CH + lane];
            acc += g0 * __int_as_float(p0.y) * wlds[((p0.x >> 20) & 15) * CH + lane];
            acc += g1 * __int_as_float(p1.y) * wlds[((p1.x >> 20) & 15) * CH + lane];
            acc += g2 * __int_as_float(p2.y) * wlds[((p2.x >> 20) & 15) * CH + lane];
            acc += g3 * __int_as_float(p3.y) * wlds[((p3.x >> 20) & 15) * CH + lane];
        }
        for (; i < e; ++i) {
            int2 p = ent_packed[i];
            acc += cur[(p.x & 0xFFFFF) * CH + lane] * __int_as_float(p.y)
                 * wlds[((p.x >> 20) & 15) * CH + lane];
        }
        float ss = acc * acc;
        #pragma unroll
        for (int o = 32; o; o >>= 1) ss += __shfl_xor(ss, o, 64);
        float y = acc / fmaxf(sqrtf(ss), 1e-12f);
        nxt[gwid * CH + lane] = y;
        res_ent[gwid * CH + lane] += y;
    } else {
        int u = gwid - N_ENTITIES;  // grid sized exactly, u < N_USERS
        int s = usr_rp[u], e = usr_rp[u + 1];
        float acc = 0.f;
        int i = s;
        for (; i + 3 < e; i += 4) {
            int2 p0 = usr_packed[i];
            int2 p1 = usr_packed[i + 1];
            int2 p2 = usr_packed[i + 2];
            int2 p3 = usr_packed[i + 3];
            acc += cur[p0.x * CH + lane] * __int_as_float(p0.y);
            acc += cur[p1.x * CH + lane] * __int_as_float(p1.y);
            acc += cur[p2.x * CH + lane] * __int_as_float(p2.y);
            acc += cur[p3.x * CH + lane] * __int_as_float(p3.y);
        }
        for (; i < e; ++i) {
            int2 p = usr_packed[i];
            acc += cur[p.x * CH + lane] * __int_as_float(p.y);
        }
        float ss = acc * acc;
        #pragma unroll
        for (int o = 32; o; o >>= 1) ss += __shfl_xor(ss, o, 64);
        float y = acc / fmaxf(sqrtf(ss), 1e-12f);
        res_usr[u * CH + lane] += y;
    }
}

extern "C" void kernel_launch(void* const* d_in, const int* in_sizes, int n_in,
                              void* d_out, int out_size, void* d_ws, size_t ws_size,
                              hipStream_t stream) {
    const float* user_emb   = (const float*)d_in[0];
    const float* entity_emb = (const float*)d_in[1];
    const float* weight     = (const float*)d_in[2];
    const float* mask       = (const float*)d_in[3];
    const float* ivals      = (const float*)d_in[4];
    const int*   edge_head  = (const int*)d_in[5];
    const int*   edge_tail  = (const int*)d_in[6];
    const int*   edge_type  = (const int*)d_in[7];
    const int*   irows      = (const int*)d_in[8];
    const int*   icols      = (const int*)d_in[9];

    float* out_entity = (float*)d_out;
    float* out_user   = (float*)d_out + (size_t)N_ENTITIES * CH;

    // ---- workspace layout ----
    float* entA       = (float*)d_ws;                             // 6.4M f
    float* entB       = entA + (size_t)N_ENTITIES * CH;           // 6.4M f
    int2*  ent_packed = (int2*)(entB + (size_t)N_ENTITIES * CH);  // 3.2M int2
    int2*  usr_packed = ent_packed + (size_t)N_EDGES;             // 2.5M int2
    int*   I          = (int*)(usr_packed + (size_t)NNZ);
    int* ent_cnt  = I;  I += N_ENTITIES;      // memset region start
    int* usr_cnt  = I;  I += N_USERS;
    int* kgb_cnt  = I;  I += 400;
    int* usb_cnt  = I;  I += 256;             // memset region end
    int* ent_rp   = I;  I += N_ENTITIES + 1;
    int* usr_rp   = I;  I += N_USERS + 1;
    int* kgb_rp   = I;  I += 408;
    int* kgb_cur  = I;  I += 400;
    int* usb_rp   = I;  I += 264;
    int* usb_cur  = I;  I += 256;
    int* partials = I;  I += 256;

    // binned scratch overlays entA/entB (used only before init)
    int* bk = (int*)entA;            // ≤ 3.2M
    int* ba = bk + N_EDGES;          // ≤ 3.2M (entA holds 6.4M ints)
    int* bb = (int*)entB;            // ≤ 3.2M

    // ---- build (identical for both hops) ----
    hipMemsetAsync(ent_cnt, 0, (size_t)(N_ENTITIES + N_USERS + 400 + 256) * sizeof(int), stream);

    hist_kernel<<<(N_EDGES + 255) / 256, 256, 0, stream>>>(edge_head, ent_cnt, N_EDGES);
    hist_kernel<<<(NNZ + 255) / 256, 256, 0, stream>>>(irows, usr_cnt, NNZ);

    bucket_sum_kernel<<<NBUCK_E, 256, 0, stream>>>(ent_cnt, kgb_cnt, N_ENTITIES);
    bucket_sum_kernel<<<NBUCK_U, 256, 0, stream>>>(usr_cnt, usb_cnt, N_USERS);

    // row_ptr scans
    scan_partA<<<256, 256, 0, stream>>>(ent_cnt, partials, N_ENTITIES, CHUNK_E);
    scan_partB<<<1, 256, 0, stream>>>(partials, ent_rp + N_ENTITIES, N_EDGES);
    scan_partC<<<256, 256, 0, stream>>>(ent_cnt, partials, ent_rp, N_ENTITIES, CHUNK_E);

    scan_partA<<<256, 256, 0, stream>>>(usr_cnt, partials, N_USERS, CHUNK_U);
    scan_partB<<<1, 256, 0, stream>>>(partials, usr_rp + N_USERS, NNZ);
    scan_partC<<<256, 256, 0, stream>>>(usr_cnt, partials, usr_rp, N_USERS, CHUNK_U);

    // bucket scans (rp + working cursor)
    small_scan<<<1, 512, 0, stream>>>(kgb_cnt, kgb_rp, kgb_cur, NBUCK_E);
    small_scan<<<1, 512, 0, stream>>>(usb_cnt, usb_rp, usb_cur, NBUCK_U);

    // KG: bin then place
    kg_pass1<<<512, 256, 0, stream>>>(edge_head, edge_tail, edge_type, mask,
                                      kgb_cur, bk, ba, bb, (N_EDGES + 511) / 512);
    bin_pass2<<<NBUCK_E, 1024, 0, stream>>>(bk, ba, bb, kgb_rp, ent_rp, N_ENTITIES, ent_packed);

    // user: bin then place (reuses binned scratch)
    usr_pass1<<<512, 256, 0, stream>>>(irows, icols, ivals,
                                       usb_cur, bk, ba, bb, (NNZ + 511) / 512);
    bin_pass2<<<NBUCK_U, 1024, 0, stream>>>(bk, ba, bb, usb_rp, usr_rp, N_USERS, usr_packed);

    // ---- init residuals + current entity state ----
    {
        int n4 = N_ENTITIES * CH / 4;
        init_kernel<<<(n4 + 255) / 256, 256, 0, stream>>>(
            (const float4*)user_emb, (const float4*)entity_emb,
            (float4*)entA, (float4*)out_entity, (float4*)out_user);
    }

    // ---- 2 hops, double-buffered entity state, merged agg ----
    const int agg_blocks = (N_ENTITIES + N_USERS) * 64 / 256;  // 37500 exact
    float* cur = entA;
    float* nxt = entB;
    for (int hop = 0; hop < 2; hop++) {
        agg_kernel<<<agg_blocks, 256, 0, stream>>>(
            cur, weight, ent_rp, ent_packed, usr_rp, usr_packed,
            nxt, out_entity, out_user);
        float* t = cur; cur = nxt; nxt = t;
    }
}